// Round 1
// baseline (587.084 us; speedup 1.0000x reference)
//
#include <hip/hip_runtime.h>

#define IN_F 8192
#define OUT_F 8192

// One block per output row. Phase 1: reduce w_sum & dot over the states row.
// Phase 2: trace update using the spike computed in phase 1.
__global__ __launch_bounds__(256) void snn_fused_kernel(
    const float* __restrict__ x,       // [IN_F] spike_input
    const float* __restrict__ states,  // [OUT_F, IN_F]
    const float* __restrict__ mp,      // [OUT_F]
    const float* __restrict__ thr,     // [OUT_F]
    const float* __restrict__ trace,   // [OUT_F, IN_F]
    float* __restrict__ out)           // spikes[OUT_F] | v[OUT_F] | thr[OUT_F] | trace[OUT_F*IN_F]
{
    const int o = blockIdx.x;
    const int t = threadIdx.x;

    __shared__ float red_ws[4];
    __shared__ float red_dot[4];
    __shared__ float s_spike;

    const float4* __restrict__ x4 = (const float4*)x;
    const float4* __restrict__ s4 = (const float4*)(states + (size_t)o * IN_F);

    // 8192 floats = 2048 float4 per row; 256 threads -> 8 float4 each (strided)
    float4 xr[8];
    float wsum = 0.0f, dot = 0.0f;
#pragma unroll
    for (int k = 0; k < 8; ++k) {
        const int idx = t + k * 256;
        const float4 xv = x4[idx];
        xr[k] = xv;
        const float4 sv = s4[idx];
        const float w0 = (sv.x > 50.0f) ? 1.0f : 0.0f;
        const float w1 = (sv.y > 50.0f) ? 1.0f : 0.0f;
        const float w2 = (sv.z > 50.0f) ? 1.0f : 0.0f;
        const float w3 = (sv.w > 50.0f) ? 1.0f : 0.0f;
        wsum += (w0 + w1) + (w2 + w3);
        dot  += (w0 * xv.x + w1 * xv.y) + (w2 * xv.z + w3 * xv.w);
    }

    // wave (64-lane) butterfly reduce
#pragma unroll
    for (int off = 32; off > 0; off >>= 1) {
        wsum += __shfl_down(wsum, off);
        dot  += __shfl_down(dot,  off);
    }
    const int wave = t >> 6;
    if ((t & 63) == 0) { red_ws[wave] = wsum; red_dot[wave] = dot; }
    __syncthreads();

    if (t == 0) {
        const float ws = (red_ws[0] + red_ws[1]) + (red_ws[2] + red_ws[3]);
        const float dt = (red_dot[0] + red_dot[1]) + (red_dot[2] + red_dot[3]);
        const float conn = fmaxf(ws, 5.0f);
        const float current = dt * (15.0f / sqrtf(conn));
        const float v = mp[o] * 0.85f + current;
        const float th = thr[o];
        const float spike = (v >= th) ? 1.0f : 0.0f;
        out[o]             = spike;
        out[OUT_F + o]     = v * (1.0f - spike) * 0.1f;
        out[2 * OUT_F + o] = fminf(fmaxf(th + (spike - 0.1f) * 0.1f, 2.0f), 15.0f);
        s_spike = spike;
    }
    __syncthreads();

    const float spike = s_spike;
    const float4* __restrict__ tr4 = (const float4*)(trace + (size_t)o * IN_F);
    float4* __restrict__ ot4 = (float4*)(out + 3 * OUT_F + (size_t)o * IN_F);
#pragma unroll
    for (int k = 0; k < 8; ++k) {
        const int idx = t + k * 256;
        const float4 tv = tr4[idx];
        const float4 xv = xr[k];
        float4 r;
        r.x = fminf(fmaxf(tv.x * 0.9f + spike * xv.x, 0.0f), 5.0f);
        r.y = fminf(fmaxf(tv.y * 0.9f + spike * xv.y, 0.0f), 5.0f);
        r.z = fminf(fmaxf(tv.z * 0.9f + spike * xv.z, 0.0f), 5.0f);
        r.w = fminf(fmaxf(tv.w * 0.9f + spike * xv.w, 0.0f), 5.0f);
        ot4[idx] = r;
    }
}

extern "C" void kernel_launch(void* const* d_in, const int* in_sizes, int n_in,
                              void* d_out, int out_size, void* d_ws, size_t ws_size,
                              hipStream_t stream) {
    const float* x      = (const float*)d_in[0];  // spike_input [8192]
    const float* states = (const float*)d_in[1];  // synapse_states [8192*8192]
    const float* mp     = (const float*)d_in[2];  // membrane_potential [8192]
    const float* thr    = (const float*)d_in[3];  // adaptive_threshold [8192]
    const float* trace  = (const float*)d_in[4];  // eligibility_trace [8192*8192]
    float* out = (float*)d_out;

    snn_fused_kernel<<<OUT_F, 256, 0, stream>>>(x, states, mp, thr, trace, out);
}

// Round 2
// 559.579 us; speedup vs baseline: 1.0492x; 1.0492x over previous
//
#include <hip/hip_runtime.h>

#define IN_F 8192
#define OUT_F 8192

typedef float v4f __attribute__((ext_vector_type(4)));

// One block per output row, single barrier.
// All row loads (x, states, trace) issue up front; spike computed redundantly
// by every thread from LDS partials; trace update stored nontemporally.
__global__ __launch_bounds__(256) void snn_fused_kernel(
    const float* __restrict__ x,       // [IN_F] spike_input
    const float* __restrict__ states,  // [OUT_F, IN_F]
    const float* __restrict__ mp,      // [OUT_F]
    const float* __restrict__ thr,     // [OUT_F]
    const float* __restrict__ trace,   // [OUT_F, IN_F]
    float* __restrict__ out)           // spikes[O] | v[O] | thr[O] | trace[O*I]
{
    const int o = blockIdx.x;
    const int t = threadIdx.x;

    __shared__ float red_ws[4];
    __shared__ float red_dot[4];

    // hoist tiny per-row scalars off the post-barrier critical path
    const float mp_o  = mp[o];
    const float thr_o = thr[o];

    const v4f* __restrict__ x4  = (const v4f*)x;
    const v4f* __restrict__ s4  = (const v4f*)(states + (size_t)o * IN_F);
    const v4f* __restrict__ tr4 = (const v4f*)(trace  + (size_t)o * IN_F);

    // 2048 float4 per row; 256 threads -> 8 float4 each (strided)
    v4f xr[8], tr[8];
    float wsum = 0.0f, dot = 0.0f;
#pragma unroll
    for (int k = 0; k < 8; ++k) {
        const int idx = t + (k << 8);
        xr[k] = x4[idx];                                    // cached (reused by all rows)
        tr[k] = __builtin_nontemporal_load(&tr4[idx]);      // streaming
        const v4f sv = __builtin_nontemporal_load(&s4[idx]); // streaming
        const float w0 = (sv[0] > 50.0f) ? 1.0f : 0.0f;
        const float w1 = (sv[1] > 50.0f) ? 1.0f : 0.0f;
        const float w2 = (sv[2] > 50.0f) ? 1.0f : 0.0f;
        const float w3 = (sv[3] > 50.0f) ? 1.0f : 0.0f;
        wsum += (w0 + w1) + (w2 + w3);
        dot  += (w0 * xr[k][0] + w1 * xr[k][1]) + (w2 * xr[k][2] + w3 * xr[k][3]);
    }

    // 64-lane wave reduce
#pragma unroll
    for (int off = 32; off > 0; off >>= 1) {
        wsum += __shfl_down(wsum, off);
        dot  += __shfl_down(dot,  off);
    }
    const int wave = t >> 6;
    if ((t & 63) == 0) { red_ws[wave] = wsum; red_dot[wave] = dot; }
    __syncthreads();

    // every thread computes spike redundantly (values are exact integers in f32,
    // so all orders agree and match the numpy reference bit-wise for the compare)
    const float ws = (red_ws[0] + red_ws[1]) + (red_ws[2] + red_ws[3]);
    const float dt = (red_dot[0] + red_dot[1]) + (red_dot[2] + red_dot[3]);
    const float conn    = fmaxf(ws, 5.0f);
    const float current = dt * (15.0f / sqrtf(conn));
    const float v       = mp_o * 0.85f + current;
    const float spike   = (v >= thr_o) ? 1.0f : 0.0f;

    if (t == 0) {
        out[o]             = spike;
        out[OUT_F + o]     = v * (1.0f - spike) * 0.1f;
        out[2 * OUT_F + o] = fminf(fmaxf(thr_o + (spike - 0.1f) * 0.1f, 2.0f), 15.0f);
    }

    v4f* __restrict__ ot4 = (v4f*)(out + 3 * OUT_F + (size_t)o * IN_F);
#pragma unroll
    for (int k = 0; k < 8; ++k) {
        const int idx = t + (k << 8);
        v4f r;
        r[0] = fminf(fmaxf(tr[k][0] * 0.9f + spike * xr[k][0], 0.0f), 5.0f);
        r[1] = fminf(fmaxf(tr[k][1] * 0.9f + spike * xr[k][1], 0.0f), 5.0f);
        r[2] = fminf(fmaxf(tr[k][2] * 0.9f + spike * xr[k][2], 0.0f), 5.0f);
        r[3] = fminf(fmaxf(tr[k][3] * 0.9f + spike * xr[k][3], 0.0f), 5.0f);
        __builtin_nontemporal_store(r, &ot4[idx]);
    }
}

extern "C" void kernel_launch(void* const* d_in, const int* in_sizes, int n_in,
                              void* d_out, int out_size, void* d_ws, size_t ws_size,
                              hipStream_t stream) {
    const float* x      = (const float*)d_in[0];  // spike_input [8192]
    const float* states = (const float*)d_in[1];  // synapse_states [8192*8192]
    const float* mp     = (const float*)d_in[2];  // membrane_potential [8192]
    const float* thr    = (const float*)d_in[3];  // adaptive_threshold [8192]
    const float* trace  = (const float*)d_in[4];  // eligibility_trace [8192*8192]
    float* out = (float*)d_out;

    snn_fused_kernel<<<OUT_F, 256, 0, stream>>>(x, states, mp, thr, trace, out);
}